// Round 3
// baseline (946.995 us; speedup 1.0000x reference)
//
#include <hip/hip_runtime.h>
#include <hip/hip_bf16.h>
#include <stdint.h>

typedef unsigned int u32;
typedef unsigned long long u64;

#define HH 50
#define WW 75
#define NPOS 3750
#define NANCH 33750
#define CAP 4096
#define RPSZ 1920000   // 3750*512 floats per k-split partial

__constant__ float c_aw[9] = {184.f,368.f,736.f,128.f,256.f,512.f,88.f,176.f,352.f};
__constant__ float c_ah[9] = {96.f,192.f,384.f,128.f,256.f,512.f,176.f,352.f,704.f};

// ---------------- weight transform: w [512][1024][9] -> wTb [16 tile][32 ch][72 f][128 oc]
// tile = ocb*4 + ks;  f = il*9 + k;  oc local to ocb block of 128
__global__ __launch_bounds__(256) void k_tw2(const float* __restrict__ w, float* __restrict__ wTb) {
  __shared__ __align__(16) float T[72*129];
  int tile = blockIdx.x;      // 0..15
  int ch   = blockIdx.y;      // 0..31
  int ocb = tile >> 2, ks = tile & 3;
  int t = threadIdx.x;
  const float* src = w + (size_t)(ocb*128)*9216 + (size_t)(ks*256 + ch*8)*9;
  #pragma unroll
  for (int i = 0; i < 36; ++i) {
    int e = t + i*256;                 // over 128 oc * 72 f
    int oc = e / 72, f = e - oc*72;
    T[f*129 + oc] = src[(size_t)oc*9216 + f];
  }
  __syncthreads();
  float* dst = wTb + ((size_t)tile*32 + ch)*9216;
  #pragma unroll
  for (int i = 0; i < 9; ++i) {
    int j = t + i*256;                 // float4 index over 2304
    int f = j >> 5, o4 = (j & 31)*4;
    float4 v = make_float4(T[f*129+o4], T[f*129+o4+1], T[f*129+o4+2], T[f*129+o4+3]);
    *(float4*)&dst[(size_t)j*4] = v;
  }
}

// ---------------- feature transpose: head [1024][3750] -> fT [3750][1024]
__global__ __launch_bounds__(256) void k_tf(const float* __restrict__ head, float* __restrict__ fT) {
  __shared__ float tile[32][33];
  int p0 = blockIdx.x*32, c0 = blockIdx.y*32;
  int tx = threadIdx.x & 31, ty = threadIdx.x >> 5;   // 32 x 8
  #pragma unroll
  for (int k = 0; k < 4; ++k) {
    int cc = c0 + ty + k*8, pp = p0 + tx;
    tile[ty + k*8][tx] = (pp < NPOS) ? head[(size_t)cc*NPOS + pp] : 0.f;
  }
  __syncthreads();
  #pragma unroll
  for (int k = 0; k < 4; ++k) {
    int pp = p0 + ty + k*8, cc = c0 + tx;
    if (pp < NPOS) fT[(size_t)pp*1024 + cc] = tile[tx][ty + k*8];
  }
}

// ---------------- 3x3 conv. grid (4 ocb, 32 rowgrp, 4 ks), block 256.
// wave task g = (rp, sub): output rows 2rp,2rp+1, cols sub*16..+15, oc pair per lane.
__global__ __launch_bounds__(256) void k_conv(const float* __restrict__ head,
                                              const float* __restrict__ wTb,
                                              float* __restrict__ rpnP) {
  __shared__ __align__(16) float Ws[9216];          // [f=il*9+k][oc 128]
  __shared__ __align__(16) float Xs[8*6*80 + 16];   // [il][rr 6][x 80] + pad
  int ocb = blockIdx.x;
  int ks  = blockIdx.z;
  int t = threadIdx.x;
  int lane = t & 63;
  int g = blockIdx.y*4 + (t >> 6);
  if (g >= 125) g = 124;              // duplicate tail waves (benign same-value writes)
  int rp  = __builtin_amdgcn_readfirstlane(g / 5);
  int sub = __builtin_amdgcn_readfirstlane(g - (g/5)*5);
  int rpA = (int)((blockIdx.y*4) / 5);
  int x0 = sub * 16;
  int rbase = 2*rpA - 1;              // global input row for Xs rr=0
  int rloc = 2*(rp - rpA);            // 0 or 2

  float a00[16], a01[16], a10[16], a11[16];
  #pragma unroll
  for (int j = 0; j < 16; ++j) { a00[j]=0.f; a01[j]=0.f; a10[j]=0.f; a11[j]=0.f; }

  const float* wsrc = wTb + (size_t)(ocb*4 + ks)*32*9216;
  int ic0 = ks*256;

  #pragma unroll 1
  for (int ch = 0; ch < 32; ++ch) {
    // stage W: 2304 float4
    #pragma unroll
    for (int i = 0; i < 9; ++i) {
      int e = t + i*256;
      *(float4*)&Ws[e*4] = *(const float4*)(wsrc + (size_t)ch*9216 + (size_t)e*4);
    }
    // stage X: 3840 floats with pad guards
    int icc = ic0 + ch*8;
    #pragma unroll
    for (int i = 0; i < 15; ++i) {
      int e = t + i*256;
      int il = e / 480; int r = e - il*480;
      int rr = r / 80;  int xx = r - rr*80;
      int sy = rbase + rr, sx = xx - 1;
      float v = 0.f;
      if (sy >= 0 && sy < HH && sx >= 0 && sx < WW)
        v = head[(size_t)(icc + il)*NPOS + sy*WW + sx];
      Xs[e] = v;
    }
    __syncthreads();
    #pragma unroll 1
    for (int il = 0; il < 8; ++il) {
      float wv0[9], wv1[9];
      #pragma unroll
      for (int k = 0; k < 9; ++k) {
        float2 w2 = *(const float2*)&Ws[(il*9 + k)*128 + 2*lane];
        wv0[k] = w2.x; wv1[k] = w2.y;
      }
      const float* xbase = &Xs[(il*6 + rloc)*80 + x0];
      #pragma unroll
      for (int ri = 0; ri < 4; ++ri) {
        // 20 floats via 5 aligned float4 broadcast reads (indices 16..19 feed
        // only dead accumulators of the partially-active last subtile)
        float4 q0 = *(const float4*)(xbase + ri*80);
        float4 q1 = *(const float4*)(xbase + ri*80 + 4);
        float4 q2 = *(const float4*)(xbase + ri*80 + 8);
        float4 q3 = *(const float4*)(xbase + ri*80 + 12);
        float4 q4 = *(const float4*)(xbase + ri*80 + 16);
        float sxv[20] = {q0.x,q0.y,q0.z,q0.w, q1.x,q1.y,q1.z,q1.w,
                         q2.x,q2.y,q2.z,q2.w, q3.x,q3.y,q3.z,q3.w,
                         q4.x,q4.y,q4.z,q4.w};
        if (ri < 3) {            // contributes to row0 with ky=ri
          #pragma unroll
          for (int kx = 0; kx < 3; ++kx) {
            float w0 = wv0[ri*3+kx], w1 = wv1[ri*3+kx];
            #pragma unroll
            for (int j = 0; j < 16; ++j) {
              a00[j] = fmaf(w0, sxv[j+kx], a00[j]);
              a01[j] = fmaf(w1, sxv[j+kx], a01[j]);
            }
          }
        }
        if (ri > 0) {            // contributes to row1 with ky=ri-1
          #pragma unroll
          for (int kx = 0; kx < 3; ++kx) {
            float w0 = wv0[(ri-1)*3+kx], w1 = wv1[(ri-1)*3+kx];
            #pragma unroll
            for (int j = 0; j < 16; ++j) {
              a10[j] = fmaf(w0, sxv[j+kx], a10[j]);
              a11[j] = fmaf(w1, sxv[j+kx], a11[j]);
            }
          }
        }
      }
    }
    __syncthreads();
  }
  float* outp = rpnP + (size_t)ks*RPSZ;
  int ocl = ocb*128 + 2*lane;
  int or0 = 2*rp;
  #pragma unroll
  for (int j = 0; j < 16; ++j) {
    int x = x0 + j;
    if (x < WW) {
      *(float2*)&outp[(size_t)(or0*WW + x)*512 + ocl]     = make_float2(a00[j], a01[j]);
      *(float2*)&outp[(size_t)((or0+1)*WW + x)*512 + ocl] = make_float2(a10[j], a11[j]);
    }
  }
}

// ---------------- 1x1 convs + softmax score + box decode; block = 16 positions
__global__ __launch_bounds__(256) void k_cls(const float* __restrict__ rp,
    const float* __restrict__ brpn,
    const float* __restrict__ w_cls, const float* __restrict__ b_cls,
    const float* __restrict__ w_bbox, const float* __restrict__ b_bbox,
    const float* __restrict__ w_tr, const float* __restrict__ b_tr,
    const float* __restrict__ iminfo,
    u32* __restrict__ sk, float* __restrict__ boxes, float* __restrict__ tpar) {
  __shared__ __align__(16) float R[128*68];     // [icg][pos*4+s], stride 68 (pad)
  __shared__ float O[16][112];
  int p0 = blockIdx.x << 4;
  int t = threadIdx.x;
  for (int e = t; e < 8192; e += 256) {
    int pos = e >> 9, ic = e & 511;
    int p = p0 + pos;
    float v = 0.f;
    if (p < NPOS) {
      size_t off = (size_t)p*512 + ic;
      v = rp[off] + rp[off + RPSZ] + rp[off + 2*(size_t)RPSZ] + rp[off + 3*(size_t)RPSZ] + brpn[ic];
      v = fmaxf(v, 0.f);
    }
    R[(ic>>2)*68 + pos*4 + (ic&3)] = v;
  }
  __syncthreads();
  int og = t >> 4, pos = t & 15;
  float acc[7];
  const float* wp[7];
  #pragma unroll
  for (int k = 0; k < 7; ++k) {
    acc[k] = 0.f;
    int o = og + (k << 4);
    if (o < 18)       wp[k] = w_cls + (size_t)o*512;
    else if (o < 54)  wp[k] = w_bbox + (size_t)(o-18)*512;
    else if (o < 108) wp[k] = w_tr + (size_t)(o-54)*512;
    else              wp[k] = w_cls;
  }
  for (int icg = 0; icg < 128; ++icg) {
    float4 xv = *(const float4*)&R[icg*68 + pos*4];
    #pragma unroll
    for (int k = 0; k < 7; ++k) {
      float4 wv = *(const float4*)(wp[k] + icg*4);
      acc[k] = fmaf(xv.x, wv.x, acc[k]);
      acc[k] = fmaf(xv.y, wv.y, acc[k]);
      acc[k] = fmaf(xv.z, wv.z, acc[k]);
      acc[k] = fmaf(xv.w, wv.w, acc[k]);
    }
  }
  #pragma unroll
  for (int k = 0; k < 7; ++k) {
    int o = og + (k << 4);
    if (o < 108) {
      float bv = (o < 18) ? b_cls[o] : (o < 54) ? b_bbox[o-18] : b_tr[o-54];
      O[pos][o] = acc[k] + bv;
    }
  }
  __syncthreads();
  if (t < 144) {
    int ps = t / 9, a = t - ps*9;
    int p = p0 + ps;
    if (p < NPOS) {
      int i = p*9 + a;
      float d = O[ps][9+a] - O[ps][a];
      float prob = 1.f / (1.f + expf(-d));
      u32 u = __float_as_uint(prob);
      sk[i] = (u & 0x80000000u) ? ~u : (u | 0x80000000u);
      int y = p / WW, x = p - y*WW;
      float aw = c_aw[a], ah = c_ah[a];
      float acx = x*16.f + 8.f, acy = y*16.f + 8.f;
      float dx = O[ps][18+a*4], dyv = O[ps][18+a*4+1], dz = O[ps][18+a*4+2], dw = O[ps][18+a*4+3];
      float pcx = dx*aw + acx, pcy = dyv*ah + acy;
      float pw = expf(dz)*aw, ph = expf(dw)*ah;
      float imh = iminfo[0], imw = iminfo[1];
      float x1 = fminf(fmaxf(pcx - 0.5f*pw, 0.f), imw - 1.f);
      float y1 = fminf(fmaxf(pcy - 0.5f*ph, 0.f), imh - 1.f);
      float x2 = fminf(fmaxf(pcx + 0.5f*pw, 0.f), imw - 1.f);
      float y2 = fminf(fmaxf(pcy + 0.5f*ph, 0.f), imh - 1.f);
      *(float4*)(boxes + (size_t)i*4) = make_float4(x1,y1,x2,y2);
      #pragma unroll
      for (int j = 0; j < 6; ++j) tpar[(size_t)i*6 + j] = O[ps][54 + a*6 + j];
    }
  }
}

// ---------------- selection: histogram -> threshold -> compact -> sort
__global__ __launch_bounds__(256) void k_hist(const u32* __restrict__ sk, u32* __restrict__ hist) {
  int i = blockIdx.x*256 + threadIdx.x;
  if (i < NANCH) atomicAdd(&hist[sk[i] >> 16], 1u);
}

__global__ __launch_bounds__(1024) void k_thresh(const u32* __restrict__ hist, u32* __restrict__ thr) {
  __shared__ u32 S[1024];
  __shared__ int tstar;
  int t = threadIdx.x;
  u32 s = 0;
  for (int j = 0; j < 64; ++j) s += hist[t*64 + j];
  S[t] = s;
  __syncthreads();
  for (int d = 1; d < 1024; d <<= 1) {
    u32 v = (t + d < 1024) ? S[t + d] : 0;
    __syncthreads();
    S[t] += v;
    __syncthreads();
  }
  if (S[t] >= 300 && (t == 1023 || S[t+1] < 300)) tstar = t;
  __syncthreads();
  if (t == 0) {
    int ts = tstar;
    u32 c = (ts < 1023) ? S[ts+1] : 0;
    int T = ts*64;
    for (int b = ts*64 + 63; b >= ts*64; --b) {
      c += hist[b];
      if (c >= 300) { T = b; break; }
    }
    thr[0] = (u32)T;
  }
}

__global__ __launch_bounds__(256) void k_compact(const u32* __restrict__ sk, const u32* __restrict__ thr,
                                                 u64* __restrict__ cand, u32* __restrict__ cnt) {
  int i = blockIdx.x*256 + threadIdx.x;
  if (i >= NANCH) return;
  u32 k = sk[i];
  if ((k >> 16) >= thr[0]) {
    u32 p = atomicAdd(cnt, 1u);
    if (p < CAP) cand[p] = ((u64)k << 32) | (u32)(~(u32)i);
  }
}

__global__ __launch_bounds__(1024) void k_sortsel(const u64* __restrict__ cand, const u32* __restrict__ cnt,
    const float* __restrict__ boxes, const float* __restrict__ tpar,
    float* __restrict__ out_rois, float* __restrict__ selb, float* __restrict__ selt) {
  __shared__ u64 A[CAP];
  int t = threadIdx.x;
  int n = min((int)cnt[0], CAP);
  for (int i = t; i < CAP; i += 1024) A[i] = (i < n) ? cand[i] : 0ull;
  __syncthreads();
  for (int k = 2; k <= CAP; k <<= 1) {
    for (int j = k >> 1; j > 0; j >>= 1) {
      for (int i = t; i < CAP; i += 1024) {
        int p = i ^ j;
        if (p > i) {
          u64 a = A[i], b = A[p];
          bool dir = (i & k) == 0;            // descending overall
          if (dir ? (a < b) : (a > b)) { A[i] = b; A[p] = a; }
        }
      }
      __syncthreads();
    }
  }
  if (t < 300) {
    u32 idx = ~((u32)A[t]);
    float4 bx = *(const float4*)(boxes + (size_t)idx*4);
    out_rois[t*5+0] = 0.f;
    out_rois[t*5+1] = bx.x; out_rois[t*5+2] = bx.y;
    out_rois[t*5+3] = bx.z; out_rois[t*5+4] = bx.w;
    *(float4*)(selb + t*4) = bx;
    #pragma unroll
    for (int j = 0; j < 6; ++j) selt[t*6+j] = tpar[(size_t)idx*6 + j];
  }
}

// ---------------- ROI pooling (14x14 bilinear -> 2x2 max) + affine transform
__global__ __launch_bounds__(256) void k_pool(const float* __restrict__ fT,
    const float* __restrict__ selb, const float* __restrict__ selt,
    float* __restrict__ outP, float* __restrict__ outTr) {
  __shared__ __align__(16) float pl[256*49];
  int r = blockIdx.y;
  int c0 = blockIdx.x << 8;
  int t = threadIdx.x;
  const float* img = fT + c0 + t;
  float bx1 = selb[r*4], by1 = selb[r*4+1], bx2 = selb[r*4+2], by2 = selb[r*4+3];
  float fx1 = bx1*0.0625f, fy1 = by1*0.0625f, fx2 = bx2*0.0625f, fy2 = by2*0.0625f;
  float t00 = (fx2-fx1)*(1.f/74.f);
  float t02 = (fx1+fx2-74.f)*(1.f/74.f);
  float t11 = (fy2-fy1)*(1.f/49.f);
  float t12 = (fy1+fy2-49.f)*(1.f/49.f);
  for (int py = 0; py < 7; ++py) {
    float m[7];
    #pragma unroll
    for (int q = 0; q < 7; ++q) m[q] = -3.4e38f;
    #pragma unroll
    for (int dy = 0; dy < 2; ++dy) {
      int sy = py*2 + dy;
      float gy = -1.f + sy*(2.f/13.f);
      float yf = (t11*gy + t12 + 1.f)*24.5f;
      float y0f = floorf(yf);
      float wy1 = yf - y0f, wy0 = 1.f - wy1;
      bool vy0 = (y0f >= 0.f && y0f <= 49.f);
      bool vy1 = (y0f >= -1.f && y0f <= 48.f);
      float yc = fminf(fmaxf(y0f, -2.f), 51.f);
      int iy0 = min(max((int)yc, 0), 49);
      int iy1 = min(max((int)yc + 1, 0), 49);
      #pragma unroll
      for (int sx = 0; sx < 14; ++sx) {
        float gx = -1.f + sx*(2.f/13.f);
        float xf = (t00*gx + t02 + 1.f)*37.f;
        float x0f = floorf(xf);
        float wx1 = xf - x0f, wx0 = 1.f - wx1;
        bool vx0 = (x0f >= 0.f && x0f <= 74.f);
        bool vx1 = (x0f >= -1.f && x0f <= 73.f);
        float xc = fminf(fmaxf(x0f, -2.f), 76.f);
        int ix0 = min(max((int)xc, 0), 74);
        int ix1 = min(max((int)xc + 1, 0), 74);
        float v00 = (vx0 && vy0) ? img[(size_t)(iy0*WW + ix0)*1024] : 0.f;
        float v10 = (vx1 && vy0) ? img[(size_t)(iy0*WW + ix1)*1024] : 0.f;
        float v01 = (vx0 && vy1) ? img[(size_t)(iy1*WW + ix0)*1024] : 0.f;
        float v11 = (vx1 && vy1) ? img[(size_t)(iy1*WW + ix1)*1024] : 0.f;
        float val = v00*(wx0*wy0) + v10*(wx1*wy0) + v01*(wx0*wy1) + v11*(wx1*wy1);
        m[sx>>1] = fmaxf(m[sx>>1], val);
      }
    }
    #pragma unroll
    for (int q = 0; q < 7; ++q) pl[t*49 + py*7 + q] = m[q];
  }
  __syncthreads();
  size_t base = (size_t)r*50176 + (size_t)c0*49;
  for (int jj = t; jj < 3136; jj += 256)
    *(float4*)(outP + base + (size_t)jj*4) = *(const float4*)&pl[jj*4];
  float T0 = selt[r*6], T1 = selt[r*6+1], T2 = selt[r*6+2];
  float T3 = selt[r*6+3], T4 = selt[r*6+4], T5 = selt[r*6+5];
  float tr[49];
  #pragma unroll
  for (int qy = 0; qy < 7; ++qy) {
    float gy = -1.f + qy*(1.f/3.f);
    #pragma unroll
    for (int qx = 0; qx < 7; ++qx) {
      float gx = -1.f + qx*(1.f/3.f);
      float xf = (T0*gx + T1*gy + T2 + 1.f)*3.f;
      float yf = (T3*gx + T4*gy + T5 + 1.f)*3.f;
      float x0f = floorf(xf), y0f = floorf(yf);
      float wx1 = xf - x0f, wx0 = 1.f - wx1;
      float wy1 = yf - y0f, wy0 = 1.f - wy1;
      bool vx0 = (x0f >= 0.f && x0f <= 6.f), vx1 = (x0f >= -1.f && x0f <= 5.f);
      bool vy0 = (y0f >= 0.f && y0f <= 6.f), vy1 = (y0f >= -1.f && y0f <= 5.f);
      float xc = fminf(fmaxf(x0f, -2.f), 8.f);
      float ycl = fminf(fmaxf(y0f, -2.f), 8.f);
      int ix0 = min(max((int)xc, 0), 6), ix1 = min(max((int)xc + 1, 0), 6);
      int iy0 = min(max((int)ycl, 0), 6), iy1 = min(max((int)ycl + 1, 0), 6);
      const float* P = &pl[t*49];
      float v00 = (vx0&&vy0) ? P[iy0*7+ix0] : 0.f;
      float v10 = (vx1&&vy0) ? P[iy0*7+ix1] : 0.f;
      float v01 = (vx0&&vy1) ? P[iy1*7+ix0] : 0.f;
      float v11 = (vx1&&vy1) ? P[iy1*7+ix1] : 0.f;
      tr[qy*7+qx] = v00*(wx0*wy0) + v10*(wx1*wy0) + v01*(wx0*wy1) + v11*(wx1*wy1);
    }
  }
  __syncthreads();
  #pragma unroll
  for (int q = 0; q < 49; ++q) pl[t*49 + q] = tr[q];
  __syncthreads();
  for (int jj = t; jj < 3136; jj += 256)
    *(float4*)(outTr + base + (size_t)jj*4) = *(const float4*)&pl[jj*4];
}

extern "C" void kernel_launch(void* const* d_in, const int* in_sizes, int n_in,
                              void* d_out, int out_size, void* d_ws, size_t ws_size,
                              hipStream_t stream) {
  (void)in_sizes; (void)n_in; (void)out_size; (void)ws_size;
  const float* head   = (const float*)d_in[0];
  const float* iminfo = (const float*)d_in[2];
  const float* w_rpn  = (const float*)d_in[3];
  const float* b_rpn  = (const float*)d_in[4];
  const float* w_cls  = (const float*)d_in[5];
  const float* b_cls  = (const float*)d_in[6];
  const float* w_bbox = (const float*)d_in[7];
  const float* b_bbox = (const float*)d_in[8];
  const float* w_tr   = (const float*)d_in[9];
  const float* b_tr   = (const float*)d_in[10];
  float* out = (float*)d_out;
  float* out_rois = out;
  float* outP = out + 1500;
  float* outT = out + 1500 + 15052800;

  char* wsp = (char*)d_ws;
  size_t off = 0;
  auto alloc = [&](size_t bytes) -> void* {
    void* p = wsp + off;
    off = (off + bytes + 255) & ~(size_t)255;
    return p;
  };
  float* wTb   = (float*)alloc(4718592ull*4);   // 16*32*72*128 ; fT aliases here later
  float* rpnP  = (float*)alloc(4ull*RPSZ*4);
  u32*   sk    = (u32*)alloc(NANCH*4);
  float* boxes = (float*)alloc((size_t)NANCH*4*4);
  float* tpar  = (float*)alloc((size_t)NANCH*6*4);
  u32*   hist  = (u32*)alloc(65536*4);
  u32*   cnt   = (u32*)alloc(256);
  u64*   cand  = (u64*)alloc(CAP*8);
  float* selb  = (float*)alloc(300*4*4);
  float* selt  = (float*)alloc(300*6*4);
  float* fT    = wTb;                            // alias: k_tf runs after k_conv

  hipMemsetAsync(hist, 0, 65536*4, stream);
  hipMemsetAsync(cnt, 0, 8, stream);

  k_tw2<<<dim3(16, 32), 256, 0, stream>>>(w_rpn, wTb);
  k_conv<<<dim3(4, 32, 4), 256, 0, stream>>>(head, wTb, rpnP);
  k_tf<<<dim3(118, 32), 256, 0, stream>>>(head, fT);
  k_cls<<<235, 256, 0, stream>>>(rpnP, b_rpn, w_cls, b_cls, w_bbox, b_bbox,
                                 w_tr, b_tr, iminfo, sk, boxes, tpar);
  k_hist<<<132, 256, 0, stream>>>(sk, hist);
  k_thresh<<<1, 1024, 0, stream>>>(hist, cnt + 1);
  k_compact<<<132, 256, 0, stream>>>(sk, cnt + 1, cand, cnt);
  k_sortsel<<<1, 1024, 0, stream>>>(cand, cnt, boxes, tpar, out_rois, selb, selt);
  k_pool<<<dim3(4, 300), 256, 0, stream>>>(fT, selb, selt, outP, outT);
}